// Round 8
// baseline (438.816 us; speedup 1.0000x reference)
//
#include <hip/hip_runtime.h>
#include <stdint.h>

#define TQs 2048
#define TKs 2048
#define DDs 512
#define NBs 8

typedef float f32x4 __attribute__((ext_vector_type(4)));
typedef float f32x2 __attribute__((ext_vector_type(2)));
typedef short bf16x8 __attribute__((ext_vector_type(8)));
typedef short bf16x4 __attribute__((ext_vector_type(4)));
typedef _Float16 half8 __attribute__((ext_vector_type(8)));

__device__ __forceinline__ unsigned short f2bf(float x){
  unsigned u = __float_as_uint(x);
  return (unsigned short)((u + 0x7fffu + ((u>>16)&1u)) >> 16);
}
__device__ __forceinline__ float bf2f(unsigned short h){
  return __uint_as_float(((unsigned)h)<<16);
}

// global -> LDS direct DMA, 16B per lane; LDS dest = uniform base + lane*16.
__device__ __forceinline__ void gload16(const void* g, void* l){
  __builtin_amdgcn_global_load_lds(
      (const __attribute__((address_space(1))) unsigned int*)(unsigned long long)(uintptr_t)g,
      (__attribute__((address_space(3))) unsigned int*)(unsigned int)(uintptr_t)l,
      16, 0, 0);
}

// K0a: k (f32) -> kf (f16)
__global__ __launch_bounds__(256) void k0_kf(const float* __restrict__ kk, _Float16* __restrict__ kf){
  const long n8 = (long)NBs*TKs*DDs/8;
  for(long i = (long)blockIdx.x*256 + threadIdx.x; i < n8; i += (long)gridDim.x*256){
    f32x4 x0 = ((const f32x4*)kk)[2*i];
    f32x4 x1 = ((const f32x4*)kk)[2*i+1];
    half8 h;
    #pragma unroll
    for(int j=0;j<4;j++){ h[j] = (_Float16)x0[j]; h[4+j] = (_Float16)x1[j]; }
    ((half8*)kf)[i] = h;
  }
}

// K0m: pack mask (int32, 0/1) into bit-words: 64 t-positions per uint64.
__global__ __launch_bounds__(256) void k0_mb(const int* __restrict__ mask, unsigned long long* __restrict__ mbits){
  const long n = (long)NBs*TQs*TKs;
  int lane = threadIdx.x & 63;
  for(long i = (long)blockIdx.x*256 + threadIdx.x; i < n; i += (long)gridDim.x*256){
    int v = mask[i];
    unsigned long long bal = __ballot(v != 0);
    if(lane == 0) mbits[i>>6] = bal;
  }
}

// K0b: v (b,t,d) f32 -> vt (b,d,t) bf16
__global__ __launch_bounds__(256) void k0_transpose_v(const float* __restrict__ v, short* __restrict__ vt){
  __shared__ float tile[64][65];
  int b = blockIdx.z;
  int t0 = blockIdx.x*64, d0 = blockIdx.y*64;
  int tid = threadIdx.x;
  int r = tid>>2, cs = (tid&3)*16;
  const float* src = v + ((long)b*TKs + t0 + r)*DDs + d0 + cs;
  #pragma unroll
  for(int i=0;i<4;i++){
    f32x4 x = ((const f32x4*)src)[i];
    tile[r][cs+4*i+0]=x[0]; tile[r][cs+4*i+1]=x[1]; tile[r][cs+4*i+2]=x[2]; tile[r][cs+4*i+3]=x[3];
  }
  __syncthreads();
  int dr = tid>>2, ts = (tid&3)*16;
  bf16x8 b0, b1;
  #pragma unroll
  for(int i=0;i<8;i++){ b0[i] = (short)f2bf(tile[ts+i][dr]); b1[i] = (short)f2bf(tile[ts+8+i][dr]); }
  short* dst = vt + ((long)b*DDs + d0 + dr)*TKs + t0 + ts;
  ((bf16x8*)dst)[0] = b0;
  ((bf16x8*)dst)[1] = b1;
}

// K0c: w (d,e) f32 -> wth/wtl (e,d) bf16 split
__global__ __launch_bounds__(256) void k0_wt(const float* __restrict__ wsrc,
                                             short* __restrict__ wth, short* __restrict__ wtl){
  __shared__ float tile[64][65];
  int d0 = blockIdx.x*64, e0 = blockIdx.y*64;
  int tid = threadIdx.x;
  int r = tid>>2, cs = (tid&3)*16;
  const float* src = wsrc + ((long)(d0 + r))*DDs + e0 + cs;
  #pragma unroll
  for(int i=0;i<4;i++){
    f32x4 x = ((const f32x4*)src)[i];
    tile[r][cs+4*i+0]=x[0]; tile[r][cs+4*i+1]=x[1]; tile[r][cs+4*i+2]=x[2]; tile[r][cs+4*i+3]=x[3];
  }
  __syncthreads();
  int er = tid>>2, ds = (tid&3)*16;
  bf16x8 h0,h1,l0,l1;
  #pragma unroll
  for(int i=0;i<8;i++){
    float x = tile[ds+i][er];
    unsigned short hh = f2bf(x);
    h0[i] = (short)hh; l0[i] = (short)f2bf(x - bf2f(hh));
  }
  #pragma unroll
  for(int i=0;i<8;i++){
    float x = tile[ds+8+i][er];
    unsigned short hh = f2bf(x);
    h1[i] = (short)hh; l1[i] = (short)f2bf(x - bf2f(hh));
  }
  short* dh = wth + ((long)(e0+er))*DDs + d0 + ds;
  short* dl = wtl + ((long)(e0+er))*DDs + d0 + ds;
  ((bf16x8*)dh)[0] = h0; ((bf16x8*)dh)[1] = h1;
  ((bf16x8*)dl)[0] = l0; ((bf16x8*)dl)[1] = l1;
}

// K1: qw = q @ W (bf16 3-term). Output: f16 hi/lo split.
__global__ __launch_bounds__(256,2) void k1_qw(const float* __restrict__ q,
                                               const short* __restrict__ wth, const short* __restrict__ wtl,
                                               _Float16* __restrict__ qwh, _Float16* __restrict__ qwl){
  __shared__ short qah[8192], qal[8192];
  __shared__ short wbh[8192], wbl[8192];
  int q0 = blockIdx.x*128, e0 = blockIdx.y*128;
  int tid = threadIdx.x, lane = tid&63, w4 = tid>>6;
  int wm = w4>>1, wn = w4&1;
  int i15 = lane&15, g4 = lane>>4;
  f32x4 acc[4][4];
  #pragma unroll
  for(int a=0;a<4;a++)
    #pragma unroll
    for(int bq=0;bq<4;bq++) acc[a][bq] = (f32x4){0.f,0.f,0.f,0.f};
  for(int k0=0;k0<DDs;k0+=64){
    __syncthreads();
    #pragma unroll
    for(int j=0;j<4;j++){
      int J = j*4 + w4;
      long so = (long)(e0 + (J>>1)*16 + i15)*DDs + k0 + ((J&1)*4 + g4)*8;
      gload16(wth + so, &wbh[J*512]);
      gload16(wtl + so, &wbl[J*512]);
    }
    #pragma unroll
    for(int j=0;j<4;j++){
      int c = j*256 + tid;
      int ci = c&15, cg = (c>>4)&3, cks = (c>>6)&1, crb = c>>7;
      const float* s = q + (long)(q0 + crb*16 + ci)*DDs + k0 + (cks*4+cg)*8;
      f32x4 x0 = ((const f32x4*)s)[0];
      f32x4 x1 = ((const f32x4*)s)[1];
      bf16x8 h, l;
      #pragma unroll
      for(int jj=0;jj<4;jj++){
        unsigned short hj = f2bf(x0[jj]);
        h[jj] = (short)hj; l[jj] = (short)f2bf(x0[jj]-bf2f(hj));
      }
      #pragma unroll
      for(int jj=0;jj<4;jj++){
        unsigned short hj = f2bf(x1[jj]);
        h[4+jj] = (short)hj; l[4+jj] = (short)f2bf(x1[jj]-bf2f(hj));
      }
      *(bf16x8*)&qah[c*8] = h;
      *(bf16x8*)&qal[c*8] = l;
    }
    __syncthreads();
    #pragma unroll
    for(int ks=0;ks<2;ks++){
      bf16x8 a_h[4], a_l[4], b_h[4], b_l[4];
      #pragma unroll
      for(int mf=0;mf<4;mf++){
        int c = ((wm*4+mf)*2+ks)*64 + lane;
        a_h[mf] = *(const bf16x8*)&qah[c*8];
        a_l[mf] = *(const bf16x8*)&qal[c*8];
      }
      #pragma unroll
      for(int nf=0;nf<4;nf++){
        int c = ((wn*4+nf)*2+ks)*64 + lane;
        b_h[nf] = *(const bf16x8*)&wbh[c*8];
        b_l[nf] = *(const bf16x8*)&wbl[c*8];
      }
      #pragma unroll
      for(int mf=0;mf<4;mf++)
      #pragma unroll
      for(int nf=0;nf<4;nf++){
        acc[mf][nf] = __builtin_amdgcn_mfma_f32_16x16x32_bf16(a_h[mf], b_h[nf], acc[mf][nf],0,0,0);
        acc[mf][nf] = __builtin_amdgcn_mfma_f32_16x16x32_bf16(a_h[mf], b_l[nf], acc[mf][nf],0,0,0);
        acc[mf][nf] = __builtin_amdgcn_mfma_f32_16x16x32_bf16(a_l[mf], b_h[nf], acc[mf][nf],0,0,0);
      }
    }
  }
  int rr = g4*4, cc = i15;
  #pragma unroll
  for(int mf=0;mf<4;mf++)
  #pragma unroll
  for(int nf=0;nf<4;nf++)
  #pragma unroll
  for(int r2=0;r2<4;r2++){
    long row = q0 + wm*64 + mf*16 + rr + r2;
    long col = e0 + wn*64 + nf*16 + cc;
    float s = acc[mf][nf][r2];
    _Float16 h = (_Float16)s;
    qwh[row*DDs + col] = h;
    qwl[row*DDs + col] = (_Float16)(s - (float)h);
  }
}

// K2a: scores = qw @ k^T, f16 2-term. 32-t K-tiles double-buffered.
// Mask read from bit-packed words (4MB, L2/L3-hot), prefetched 1 tile ahead.
__global__ __launch_bounds__(256,2) void k2a(const _Float16* __restrict__ qwh, const _Float16* __restrict__ qwl,
                                             const _Float16* __restrict__ kf,
                                             const unsigned long long* __restrict__ mbits,
                                             float* __restrict__ attn,
                                             float* __restrict__ m_ws, float* __restrict__ l_ws){
  __shared__ _Float16 kb[2][16384];   // 2 x 32KB
  int rb = blockIdx.x;                // 0..255
  int chunk = blockIdx.y;             // 0..1
  int tid = threadIdx.x, lane = tid&63, w = tid>>6;
  int b = rb>>5;
  long qrow0 = (long)rb*64 + w*16;
  int i15 = lane&15, g4 = lane>>4;
  half8 ah[16], al[16];
  {
    const _Float16* ph = qwh + (qrow0 + i15)*DDs + g4*8;
    const _Float16* pl = qwl + (qrow0 + i15)*DDs + g4*8;
    #pragma unroll
    for(int kc=0;kc<16;kc++){
      ah[kc] = *(const half8*)(ph + kc*32);
      al[kc] = *(const half8*)(pl + kc*32);
    }
  }
  float m_st[4], l_st[4];
  #pragma unroll
  for(int r=0;r<4;r++){ m_st[r]=-1e30f; l_st[r]=0.f; }
  const _Float16* kbase = kf + (long)b*TKs*DDs;
  unsigned long long wb_pf[4];
  // prologue: stage tile 0, prefetch mask word 0
  {
    int t0 = chunk*1024;
    #pragma unroll
    for(int j=0;j<8;j++){
      int J = j*4 + w;
      long so = (long)(t0 + ((J>>4)<<4) + i15)*DDs + (J&15)*32 + g4*8;
      gload16(kbase + so, &kb[0][J*512]);
    }
    #pragma unroll
    for(int r=0;r<4;r++)
      wb_pf[r] = mbits[(qrow0 + g4*4 + r)*(TKs/64) + (t0>>6)];
  }
  __syncthreads();
  int cur = 0;
  for(int it=0; it<32; ++it){
    int t0 = chunk*1024 + it*32;
    if(it < 31){
      int t1 = t0 + 32;
      #pragma unroll
      for(int j=0;j<8;j++){
        int J = j*4 + w;
        long so = (long)(t1 + ((J>>4)<<4) + i15)*DDs + (J&15)*32 + g4*8;
        gload16(kbase + so, &kb[cur^1][J*512]);
      }
    }
    unsigned long long wb[4];
    #pragma unroll
    for(int r=0;r<4;r++) wb[r] = wb_pf[r];
    if(it < 31){
      int t1 = t0 + 32;
      #pragma unroll
      for(int r=0;r<4;r++)
        wb_pf[r] = mbits[(qrow0 + g4*4 + r)*(TKs/64) + (t1>>6)];
    }
    f32x4 acc[2];
    acc[0]=(f32x4){0.f,0.f,0.f,0.f}; acc[1]=(f32x4){0.f,0.f,0.f,0.f};
    #pragma unroll
    for(int ks=0;ks<16;ks++){
      #pragma unroll
      for(int nf=0;nf<2;nf++){
        half8 bh = *(const half8*)&kb[cur][((nf*16+ks)*64 + lane)*8];
        acc[nf] = __builtin_amdgcn_mfma_f32_16x16x32_f16(ah[ks], bh, acc[nf],0,0,0);
        acc[nf] = __builtin_amdgcn_mfma_f32_16x16x32_f16(al[ks], bh, acc[nf],0,0,0);
      }
    }
    int hsh = (t0 & 32);
    #pragma unroll
    for(int r=0;r<4;r++){
      float s0 = acc[0][r];
      float s1 = acc[1][r];
      if((wb[r] >> (hsh + i15)) & 1ULL) s0 = -3e38f;
      if((wb[r] >> (hsh + 16 + i15)) & 1ULL) s1 = -3e38f;
      float mo = m_st[r];
      float mn = fmaxf(mo, fmaxf(s0,s1));
      l_st[r] = l_st[r]*__expf(mo-mn) + __expf(s0-mn) + __expf(s1-mn);
      m_st[r] = mn;
      long row = qrow0 + g4*4 + r;
      attn[row*TKs + t0 + i15] = s0;
      attn[row*TKs + t0 + 16 + i15] = s1;
    }
    __syncthreads();
    cur ^= 1;
  }
  // one-time 16-lane merge of (m,l)
  #pragma unroll
  for(int r=0;r<4;r++){
    #pragma unroll
    for(int d=1; d<16; d<<=1){
      float m2 = __shfl_xor(m_st[r], d, 16);
      float l2 = __shfl_xor(l_st[r], d, 16);
      float mn = fmaxf(m_st[r], m2);
      l_st[r] = l_st[r]*__expf(m_st[r]-mn) + l2*__expf(m2-mn);
      m_st[r] = mn;
    }
  }
  if(i15==0){
    #pragma unroll
    for(int r=0;r<4;r++){
      long row = qrow0 + g4*4 + r;
      m_ws[row*2 + chunk] = m_st[r];
      l_ws[row*2 + chunk] = l_st[r];
    }
  }
}

// K2b: PV ONLY, fully wave-independent, READ-ONLY on S.
// 1 wave = 32 rows x 128 dv. No LDS, no barriers. S (raw) and V both
// depth-1 register-prefetched; P computed in registers (exp) and fed
// straight to MFMA. attention output is written later by k2c.
__global__ __launch_bounds__(64,2) void k2b(const short* __restrict__ vt, const float* __restrict__ m_ws,
                                            const float* __restrict__ l_ws, const float* __restrict__ attn,
                                            float* __restrict__ outp){
  int bid = blockIdx.x;            // 2048 = 8 b x 64 rg x 4 dg
  int b  = bid >> 8;
  int rg = (bid >> 2) & 63;
  int dg = bid & 3;
  long row0 = (long)b*TQs + rg*32;
  int dv0 = dg*128;
  int lane = threadIdx.x;
  int i15 = lane & 15, g4 = lane >> 4;
  // per-lane row stats (rows i15 and 16+i15 of the group)
  float M[2], RL[2];
  #pragma unroll
  for(int mf=0; mf<2; mf++){
    long row = row0 + mf*16 + i15;
    float m0 = m_ws[row*2+0], m1 = m_ws[row*2+1];
    float Mm = fmaxf(m0, m1);
    float L = l_ws[row*2+0]*__expf(m0-Mm) + l_ws[row*2+1]*__expf(m1-Mm);
    M[mf] = Mm; RL[mf] = 1.0f/L;
  }
  const float* sp0 = attn + (row0 + i15)*TKs + g4*8;
  const float* sp1 = attn + (row0 + 16 + i15)*TKs + g4*8;
  const short* vp = vt + ((long)b*DDs + dv0 + i15)*TKs + g4*8;
  // prologue: S tile 0 and V tile 0 into regs
  f32x4 sn00 = ((const f32x4*)sp0)[0], sn01 = ((const f32x4*)sp0)[1];
  f32x4 sn10 = ((const f32x4*)sp1)[0], sn11 = ((const f32x4*)sp1)[1];
  bf16x8 bvn[8];
  #pragma unroll
  for(int nf=0;nf<8;nf++)
    bvn[nf] = *(const bf16x8*)(vp + (long)nf*16*TKs);
  f32x4 acc[2][8];
  #pragma unroll
  for(int mf=0;mf<2;mf++)
    #pragma unroll
    for(int nf=0;nf<8;nf++) acc[mf][nf] = (f32x4){0.f,0.f,0.f,0.f};
  for(int it=0; it<64; ++it){
    int t0 = it*32;
    f32x4 sc00 = sn00, sc01 = sn01, sc10 = sn10, sc11 = sn11;
    bf16x8 bv[8];
    #pragma unroll
    for(int nf=0;nf<8;nf++) bv[nf] = bvn[nf];
    if(it < 63){
      sn00 = *(const f32x4*)(sp0 + t0 + 32);
      sn01 = *(const f32x4*)(sp0 + t0 + 36);
      sn10 = *(const f32x4*)(sp1 + t0 + 32);
      sn11 = *(const f32x4*)(sp1 + t0 + 36);
      #pragma unroll
      for(int nf=0;nf<8;nf++)
        bvn[nf] = *(const bf16x8*)(vp + (long)nf*16*TKs + t0 + 32);
    }
    // P fragments in registers (no attn write)
    bf16x8 pf[2];
    #pragma unroll
    for(int mf=0;mf<2;mf++){
      f32x4 s0 = mf ? sc10 : sc00;
      f32x4 s1 = mf ? sc11 : sc01;
      bf16x8 p;
      #pragma unroll
      for(int j=0;j<4;j++){
        p[j]   = (short)f2bf(__expf(s0[j]-M[mf])*RL[mf]);
        p[4+j] = (short)f2bf(__expf(s1[j]-M[mf])*RL[mf]);
      }
      pf[mf] = p;
    }
    #pragma unroll
    for(int mf=0;mf<2;mf++)
      #pragma unroll
      for(int nf=0;nf<8;nf++)
        acc[mf][nf] = __builtin_amdgcn_mfma_f32_16x16x32_bf16(pf[mf], bv[nf], acc[mf][nf],0,0,0);
  }
  #pragma unroll
  for(int mf=0;mf<2;mf++)
  #pragma unroll
  for(int nf=0;nf<8;nf++)
  #pragma unroll
  for(int r=0;r<4;r++)
    outp[(row0 + mf*16 + g4*4 + r)*DDs + dv0 + nf*16 + i15] = acc[mf][nf][r];
}

// K2c: streaming normalize S -> attention (in place). Each f32x4 touched
// by exactly one thread; runs after k2b (same stream => ordered).
__global__ __launch_bounds__(256) void k2c(const float* __restrict__ m_ws, const float* __restrict__ l_ws,
                                           float* __restrict__ attn){
  const long nv = (long)NBs*TQs*TKs/4;   // 8,388,608 f32x4 groups
  for(long i = (long)blockIdx.x*256 + threadIdx.x; i < nv; i += (long)gridDim.x*256){
    long row = i >> 9;                   // (i*4) / 2048
    float m0 = m_ws[row*2+0], m1 = m_ws[row*2+1];
    float M = fmaxf(m0, m1);
    float L = l_ws[row*2+0]*__expf(m0-M) + l_ws[row*2+1]*__expf(m1-M);
    float RL = 1.0f/L;
    f32x4 s = ((const f32x4*)attn)[i];
    f32x4 a;
    #pragma unroll
    for(int j=0;j<4;j++) a[j] = __expf(s[j]-M)*RL;
    ((f32x4*)attn)[i] = a;
  }
}

extern "C" void kernel_launch(void* const* d_in, const int* in_sizes, int n_in,
                              void* d_out, int out_size, void* d_ws, size_t ws_size,
                              hipStream_t stream) {
  const float* q    = (const float*)d_in[0];
  const float* k    = (const float*)d_in[1];
  const float* v    = (const float*)d_in[2];
  const int*   mask = (const int*)d_in[3];
  const float* wsrc = (const float*)d_in[4];
  float* outp = (float*)d_out;
  float* attn = (float*)d_out + (long)NBs*TQs*DDs;
  char* ws = (char*)d_ws;
  const long NE = (long)NBs*TKs*DDs;      // 8,388,608 elements
  _Float16* kf  = (_Float16*)ws;                 // 2NE bytes
  short*    vt  = (short*)(ws + 2*NE);           // 2NE bytes
  _Float16* qwh = (_Float16*)(ws + 4*NE);        // 2NE bytes
  _Float16* qwl = (_Float16*)(ws + 6*NE);        // 2NE bytes
  float* m_ws = (float*)(ws + 8*NE);             // 32768 f32
  float* l_ws = (float*)(ws + 8*NE + 65536*4);
  unsigned long long* mbits = (unsigned long long*)(ws + 8*NE + 1048576);  // 4MB
  // wt split lives at the head of the attn region (dead before k2a overwrites it)
  short* wth = (short*)attn;
  short* wtl = (short*)attn + 262144;
  hipLaunchKernelGGL(k0_kf,          dim3(1024),    dim3(256), 0, stream, k, kf);
  hipLaunchKernelGGL(k0_mb,          dim3(2048),    dim3(256), 0, stream, mask, mbits);
  hipLaunchKernelGGL(k0_transpose_v, dim3(32,8,8),  dim3(256), 0, stream, v, vt);
  hipLaunchKernelGGL(k0_wt,          dim3(8,8),     dim3(256), 0, stream, wsrc, wth, wtl);
  hipLaunchKernelGGL(k1_qw,          dim3(128,4),   dim3(256), 0, stream, q, wth, wtl, qwh, qwl);
  hipLaunchKernelGGL(k2a,            dim3(256,2),   dim3(256), 0, stream, qwh, qwl, kf, mbits, attn, m_ws, l_ws);
  hipLaunchKernelGGL(k2b,            dim3(2048),    dim3(64),  0, stream, vt, m_ws, l_ws, attn, outp);
  hipLaunchKernelGGL(k2c,            dim3(2048),    dim3(256), 0, stream, m_ws, l_ws, attn);
}

// Round 9
// 410.700 us; speedup vs baseline: 1.0685x; 1.0685x over previous
//
#include <hip/hip_runtime.h>
#include <stdint.h>

#define TQs 2048
#define TKs 2048
#define DDs 512
#define NBs 8

typedef float f32x4 __attribute__((ext_vector_type(4)));
typedef short bf16x8 __attribute__((ext_vector_type(8)));
typedef short bf16x4 __attribute__((ext_vector_type(4)));
typedef _Float16 half8 __attribute__((ext_vector_type(8)));

__device__ __forceinline__ unsigned short f2bf(float x){
  unsigned u = __float_as_uint(x);
  return (unsigned short)((u + 0x7fffu + ((u>>16)&1u)) >> 16);
}
__device__ __forceinline__ float bf2f(unsigned short h){
  return __uint_as_float(((unsigned)h)<<16);
}

// global -> LDS direct DMA, 16B per lane; LDS dest = uniform base + lane*16.
__device__ __forceinline__ void gload16(const void* g, void* l){
  __builtin_amdgcn_global_load_lds(
      (const __attribute__((address_space(1))) unsigned int*)(unsigned long long)(uintptr_t)g,
      (__attribute__((address_space(3))) unsigned int*)(unsigned int)(uintptr_t)l,
      16, 0, 0);
}

// K0a: k (f32) -> kf (f16)
__global__ __launch_bounds__(256) void k0_kf(const float* __restrict__ kk, _Float16* __restrict__ kf){
  const long n8 = (long)NBs*TKs*DDs/8;
  for(long i = (long)blockIdx.x*256 + threadIdx.x; i < n8; i += (long)gridDim.x*256){
    f32x4 x0 = ((const f32x4*)kk)[2*i];
    f32x4 x1 = ((const f32x4*)kk)[2*i+1];
    half8 h;
    #pragma unroll
    for(int j=0;j<4;j++){ h[j] = (_Float16)x0[j]; h[4+j] = (_Float16)x1[j]; }
    ((half8*)kf)[i] = h;
  }
}

// K0m: pack mask (int32, 0/1) into bit-words: 64 t-positions per uint64.
__global__ __launch_bounds__(256) void k0_mb(const int* __restrict__ mask, unsigned long long* __restrict__ mbits){
  const long n = (long)NBs*TQs*TKs;
  int lane = threadIdx.x & 63;
  for(long i = (long)blockIdx.x*256 + threadIdx.x; i < n; i += (long)gridDim.x*256){
    int v = mask[i];
    unsigned long long bal = __ballot(v != 0);
    if(lane == 0) mbits[i>>6] = bal;
  }
}

// K0b: v (b,t,d) f32 -> vt (b,d,t) bf16
__global__ __launch_bounds__(256) void k0_transpose_v(const float* __restrict__ v, short* __restrict__ vt){
  __shared__ float tile[64][65];
  int b = blockIdx.z;
  int t0 = blockIdx.x*64, d0 = blockIdx.y*64;
  int tid = threadIdx.x;
  int r = tid>>2, cs = (tid&3)*16;
  const float* src = v + ((long)b*TKs + t0 + r)*DDs + d0 + cs;
  #pragma unroll
  for(int i=0;i<4;i++){
    f32x4 x = ((const f32x4*)src)[i];
    tile[r][cs+4*i+0]=x[0]; tile[r][cs+4*i+1]=x[1]; tile[r][cs+4*i+2]=x[2]; tile[r][cs+4*i+3]=x[3];
  }
  __syncthreads();
  int dr = tid>>2, ts = (tid&3)*16;
  bf16x8 b0, b1;
  #pragma unroll
  for(int i=0;i<8;i++){ b0[i] = (short)f2bf(tile[ts+i][dr]); b1[i] = (short)f2bf(tile[ts+8+i][dr]); }
  short* dst = vt + ((long)b*DDs + d0 + dr)*TKs + t0 + ts;
  ((bf16x8*)dst)[0] = b0;
  ((bf16x8*)dst)[1] = b1;
}

// K0c: w (d,e) f32 -> wth/wtl (e,d) bf16 split
__global__ __launch_bounds__(256) void k0_wt(const float* __restrict__ wsrc,
                                             short* __restrict__ wth, short* __restrict__ wtl){
  __shared__ float tile[64][65];
  int d0 = blockIdx.x*64, e0 = blockIdx.y*64;
  int tid = threadIdx.x;
  int r = tid>>2, cs = (tid&3)*16;
  const float* src = wsrc + ((long)(d0 + r))*DDs + e0 + cs;
  #pragma unroll
  for(int i=0;i<4;i++){
    f32x4 x = ((const f32x4*)src)[i];
    tile[r][cs+4*i+0]=x[0]; tile[r][cs+4*i+1]=x[1]; tile[r][cs+4*i+2]=x[2]; tile[r][cs+4*i+3]=x[3];
  }
  __syncthreads();
  int er = tid>>2, ds = (tid&3)*16;
  bf16x8 h0,h1,l0,l1;
  #pragma unroll
  for(int i=0;i<8;i++){
    float x = tile[ds+i][er];
    unsigned short hh = f2bf(x);
    h0[i] = (short)hh; l0[i] = (short)f2bf(x - bf2f(hh));
  }
  #pragma unroll
  for(int i=0;i<8;i++){
    float x = tile[ds+8+i][er];
    unsigned short hh = f2bf(x);
    h1[i] = (short)hh; l1[i] = (short)f2bf(x - bf2f(hh));
  }
  short* dh = wth + ((long)(e0+er))*DDs + d0 + ds;
  short* dl = wtl + ((long)(e0+er))*DDs + d0 + ds;
  ((bf16x8*)dh)[0] = h0; ((bf16x8*)dh)[1] = h1;
  ((bf16x8*)dl)[0] = l0; ((bf16x8*)dl)[1] = l1;
}

// K1: qw = q @ W (bf16 3-term). Output: f16 hi/lo split.
__global__ __launch_bounds__(256,2) void k1_qw(const float* __restrict__ q,
                                               const short* __restrict__ wth, const short* __restrict__ wtl,
                                               _Float16* __restrict__ qwh, _Float16* __restrict__ qwl){
  __shared__ short qah[8192], qal[8192];
  __shared__ short wbh[8192], wbl[8192];
  int q0 = blockIdx.x*128, e0 = blockIdx.y*128;
  int tid = threadIdx.x, lane = tid&63, w4 = tid>>6;
  int wm = w4>>1, wn = w4&1;
  int i15 = lane&15, g4 = lane>>4;
  f32x4 acc[4][4];
  #pragma unroll
  for(int a=0;a<4;a++)
    #pragma unroll
    for(int bq=0;bq<4;bq++) acc[a][bq] = (f32x4){0.f,0.f,0.f,0.f};
  for(int k0=0;k0<DDs;k0+=64){
    __syncthreads();
    #pragma unroll
    for(int j=0;j<4;j++){
      int J = j*4 + w4;
      long so = (long)(e0 + (J>>1)*16 + i15)*DDs + k0 + ((J&1)*4 + g4)*8;
      gload16(wth + so, &wbh[J*512]);
      gload16(wtl + so, &wbl[J*512]);
    }
    #pragma unroll
    for(int j=0;j<4;j++){
      int c = j*256 + tid;
      int ci = c&15, cg = (c>>4)&3, cks = (c>>6)&1, crb = c>>7;
      const float* s = q + (long)(q0 + crb*16 + ci)*DDs + k0 + (cks*4+cg)*8;
      f32x4 x0 = ((const f32x4*)s)[0];
      f32x4 x1 = ((const f32x4*)s)[1];
      bf16x8 h, l;
      #pragma unroll
      for(int jj=0;jj<4;jj++){
        unsigned short hj = f2bf(x0[jj]);
        h[jj] = (short)hj; l[jj] = (short)f2bf(x0[jj]-bf2f(hj));
      }
      #pragma unroll
      for(int jj=0;jj<4;jj++){
        unsigned short hj = f2bf(x1[jj]);
        h[4+jj] = (short)hj; l[4+jj] = (short)f2bf(x1[jj]-bf2f(hj));
      }
      *(bf16x8*)&qah[c*8] = h;
      *(bf16x8*)&qal[c*8] = l;
    }
    __syncthreads();
    #pragma unroll
    for(int ks=0;ks<2;ks++){
      bf16x8 a_h[4], a_l[4], b_h[4], b_l[4];
      #pragma unroll
      for(int mf=0;mf<4;mf++){
        int c = ((wm*4+mf)*2+ks)*64 + lane;
        a_h[mf] = *(const bf16x8*)&qah[c*8];
        a_l[mf] = *(const bf16x8*)&qal[c*8];
      }
      #pragma unroll
      for(int nf=0;nf<4;nf++){
        int c = ((wn*4+nf)*2+ks)*64 + lane;
        b_h[nf] = *(const bf16x8*)&wbh[c*8];
        b_l[nf] = *(const bf16x8*)&wbl[c*8];
      }
      #pragma unroll
      for(int mf=0;mf<4;mf++)
      #pragma unroll
      for(int nf=0;nf<4;nf++){
        acc[mf][nf] = __builtin_amdgcn_mfma_f32_16x16x32_bf16(a_h[mf], b_h[nf], acc[mf][nf],0,0,0);
        acc[mf][nf] = __builtin_amdgcn_mfma_f32_16x16x32_bf16(a_h[mf], b_l[nf], acc[mf][nf],0,0,0);
        acc[mf][nf] = __builtin_amdgcn_mfma_f32_16x16x32_bf16(a_l[mf], b_h[nf], acc[mf][nf],0,0,0);
      }
    }
  }
  int rr = g4*4, cc = i15;
  #pragma unroll
  for(int mf=0;mf<4;mf++)
  #pragma unroll
  for(int nf=0;nf<4;nf++)
  #pragma unroll
  for(int r2=0;r2<4;r2++){
    long row = q0 + wm*64 + mf*16 + rr + r2;
    long col = e0 + wn*64 + nf*16 + cc;
    float s = acc[mf][nf][r2];
    _Float16 h = (_Float16)s;
    qwh[row*DDs + col] = h;
    qwl[row*DDs + col] = (_Float16)(s - (float)h);
  }
}

// K2a: scores = qw @ k^T, f16 2-term. 32-t K-tiles double-buffered.
// Mask read from bit-packed words (4MB, L2/L3-hot), prefetched 1 tile ahead.
__global__ __launch_bounds__(256,2) void k2a(const _Float16* __restrict__ qwh, const _Float16* __restrict__ qwl,
                                             const _Float16* __restrict__ kf,
                                             const unsigned long long* __restrict__ mbits,
                                             float* __restrict__ attn,
                                             float* __restrict__ m_ws, float* __restrict__ l_ws){
  __shared__ _Float16 kb[2][16384];   // 2 x 32KB
  int rb = blockIdx.x;                // 0..255
  int chunk = blockIdx.y;             // 0..1
  int tid = threadIdx.x, lane = tid&63, w = tid>>6;
  int b = rb>>5;
  long qrow0 = (long)rb*64 + w*16;
  int i15 = lane&15, g4 = lane>>4;
  half8 ah[16], al[16];
  {
    const _Float16* ph = qwh + (qrow0 + i15)*DDs + g4*8;
    const _Float16* pl = qwl + (qrow0 + i15)*DDs + g4*8;
    #pragma unroll
    for(int kc=0;kc<16;kc++){
      ah[kc] = *(const half8*)(ph + kc*32);
      al[kc] = *(const half8*)(pl + kc*32);
    }
  }
  float m_st[4], l_st[4];
  #pragma unroll
  for(int r=0;r<4;r++){ m_st[r]=-1e30f; l_st[r]=0.f; }
  const _Float16* kbase = kf + (long)b*TKs*DDs;
  unsigned long long wb_pf[4];
  // prologue: stage tile 0, prefetch mask word 0
  {
    int t0 = chunk*1024;
    #pragma unroll
    for(int j=0;j<8;j++){
      int J = j*4 + w;
      long so = (long)(t0 + ((J>>4)<<4) + i15)*DDs + (J&15)*32 + g4*8;
      gload16(kbase + so, &kb[0][J*512]);
    }
    #pragma unroll
    for(int r=0;r<4;r++)
      wb_pf[r] = mbits[(qrow0 + g4*4 + r)*(TKs/64) + (t0>>6)];
  }
  __syncthreads();
  int cur = 0;
  for(int it=0; it<32; ++it){
    int t0 = chunk*1024 + it*32;
    if(it < 31){
      int t1 = t0 + 32;
      #pragma unroll
      for(int j=0;j<8;j++){
        int J = j*4 + w;
        long so = (long)(t1 + ((J>>4)<<4) + i15)*DDs + (J&15)*32 + g4*8;
        gload16(kbase + so, &kb[cur^1][J*512]);
      }
    }
    unsigned long long wb[4];
    #pragma unroll
    for(int r=0;r<4;r++) wb[r] = wb_pf[r];
    if(it < 31){
      int t1 = t0 + 32;
      #pragma unroll
      for(int r=0;r<4;r++)
        wb_pf[r] = mbits[(qrow0 + g4*4 + r)*(TKs/64) + (t1>>6)];
    }
    f32x4 acc[2];
    acc[0]=(f32x4){0.f,0.f,0.f,0.f}; acc[1]=(f32x4){0.f,0.f,0.f,0.f};
    #pragma unroll
    for(int ks=0;ks<16;ks++){
      #pragma unroll
      for(int nf=0;nf<2;nf++){
        half8 bh = *(const half8*)&kb[cur][((nf*16+ks)*64 + lane)*8];
        acc[nf] = __builtin_amdgcn_mfma_f32_16x16x32_f16(ah[ks], bh, acc[nf],0,0,0);
        acc[nf] = __builtin_amdgcn_mfma_f32_16x16x32_f16(al[ks], bh, acc[nf],0,0,0);
      }
    }
    int hsh = (t0 & 32);
    #pragma unroll
    for(int r=0;r<4;r++){
      float s0 = acc[0][r];
      float s1 = acc[1][r];
      if((wb[r] >> (hsh + i15)) & 1ULL) s0 = -3e38f;
      if((wb[r] >> (hsh + 16 + i15)) & 1ULL) s1 = -3e38f;
      float mo = m_st[r];
      float mn = fmaxf(mo, fmaxf(s0,s1));
      l_st[r] = l_st[r]*__expf(mo-mn) + __expf(s0-mn) + __expf(s1-mn);
      m_st[r] = mn;
      long row = qrow0 + g4*4 + r;
      attn[row*TKs + t0 + i15] = s0;
      attn[row*TKs + t0 + 16 + i15] = s1;
    }
    __syncthreads();
    cur ^= 1;
  }
  // one-time 16-lane merge of (m,l)
  #pragma unroll
  for(int r=0;r<4;r++){
    #pragma unroll
    for(int d=1; d<16; d<<=1){
      float m2 = __shfl_xor(m_st[r], d, 16);
      float l2 = __shfl_xor(l_st[r], d, 16);
      float mn = fmaxf(m_st[r], m2);
      l_st[r] = l_st[r]*__expf(m_st[r]-mn) + l2*__expf(m2-mn);
      m_st[r] = mn;
    }
  }
  if(i15==0){
    #pragma unroll
    for(int r=0;r<4;r++){
      long row = qrow0 + g4*4 + r;
      m_ws[row*2 + chunk] = m_st[r];
      l_ws[row*2 + chunk] = l_st[r];
    }
  }
}

// K2b: fused normalize + attention-write + PV. Block = 4 waves owns 32 rows
// (exclusive) x 512 dv x all t. Wave w: dv slice w*128; every wave reads the
// full S strip (L2 for 3 of 4) and computes P redundantly; wave w alone
// writes normalized attention for t-quarter w, LAGGED one tile behind the
// reads, with a raw s_barrier (no vmcnt drain) keeping waves in lockstep.
// b = bid&7 pins each vt[b] slice (2MB) to one XCD's L2.
__global__ __launch_bounds__(256) void k2b(const short* __restrict__ vt, const float* __restrict__ m_ws,
                                           const float* __restrict__ l_ws, float* __restrict__ attn,
                                           float* __restrict__ outp){
  int bid = blockIdx.x;            // 512 = 8 b (XCD-pinned) x 64 row-tiles
  int b  = bid & 7;
  int rt = bid >> 3;
  long row0 = (long)b*TQs + rt*32;
  int tid = threadIdx.x;
  int w = tid >> 6, lane = tid & 63;
  int i15 = lane & 15, g4 = lane >> 4;
  int dv0 = w*128;
  // per-lane row stats (rows i15 and 16+i15 of the strip)
  float M[2], RL[2];
  #pragma unroll
  for(int mf=0; mf<2; mf++){
    long row = row0 + mf*16 + i15;
    float m0 = m_ws[row*2+0], m1 = m_ws[row*2+1];
    float Mm = fmaxf(m0, m1);
    float L = l_ws[row*2+0]*__expf(m0-Mm) + l_ws[row*2+1]*__expf(m1-Mm);
    M[mf] = Mm; RL[mf] = 1.0f/L;
  }
  float* sp0 = attn + (row0 + i15)*TKs + g4*8;
  float* sp1 = attn + (row0 + 16 + i15)*TKs + g4*8;
  const short* vp = vt + ((long)b*DDs + dv0 + i15)*TKs + g4*8;
  // prologue: S tile 0 and V tile 0 into regs
  f32x4 sn00 = ((const f32x4*)sp0)[0], sn01 = ((const f32x4*)sp0)[1];
  f32x4 sn10 = ((const f32x4*)sp1)[0], sn11 = ((const f32x4*)sp1)[1];
  bf16x8 bvn[8];
  #pragma unroll
  for(int nf=0;nf<8;nf++)
    bvn[nf] = *(const bf16x8*)(vp + (long)nf*16*TKs);
  f32x4 acc[2][8];
  #pragma unroll
  for(int mf=0;mf<2;mf++)
    #pragma unroll
    for(int nf=0;nf<8;nf++) acc[mf][nf] = (f32x4){0.f,0.f,0.f,0.f};
  f32x4 aw00, aw01, aw10, aw11;   // lagged normalized values (tile it-1)
  for(int it=0; it<64; ++it){
    int t0 = it*32;
    f32x4 sc00 = sn00, sc01 = sn01, sc10 = sn10, sc11 = sn11;
    bf16x8 bv[8];
    #pragma unroll
    for(int nf=0;nf<8;nf++) bv[nf] = bvn[nf];
    if(it < 63){
      sn00 = *(const f32x4*)(sp0 + t0 + 32);
      sn01 = *(const f32x4*)(sp0 + t0 + 36);
      sn10 = *(const f32x4*)(sp1 + t0 + 32);
      sn11 = *(const f32x4*)(sp1 + t0 + 36);
      #pragma unroll
      for(int nf=0;nf<8;nf++)
        bvn[nf] = *(const bf16x8*)(vp + (long)nf*16*TKs + t0 + 32);
    }
    // write LAGGED tile (it-1) — all waves passed barrier(it-1), so every
    // wave already consumed tile it-1's raw S into registers.
    if(it > 0 && ((it-1)>>4) == w){
      int tp = (it-1)*32;
      *(f32x4*)(sp0 + tp)     = aw00;
      *(f32x4*)(sp0 + tp + 4) = aw01;
      *(f32x4*)(sp1 + tp)     = aw10;
      *(f32x4*)(sp1 + tp + 4) = aw11;
    }
    // normalize current tile in registers; pack P fragments
    bf16x8 pf[2];
    {
      f32x4 a0, a1;
      #pragma unroll
      for(int j=0;j<4;j++){ a0[j] = __expf(sc00[j]-M[0])*RL[0]; a1[j] = __expf(sc01[j]-M[0])*RL[0]; }
      aw00 = a0; aw01 = a1;
      bf16x8 p;
      #pragma unroll
      for(int j=0;j<4;j++){ p[j] = (short)f2bf(a0[j]); p[4+j] = (short)f2bf(a1[j]); }
      pf[0] = p;
      #pragma unroll
      for(int j=0;j<4;j++){ a0[j] = __expf(sc10[j]-M[1])*RL[1]; a1[j] = __expf(sc11[j]-M[1])*RL[1]; }
      aw10 = a0; aw11 = a1;
      #pragma unroll
      for(int j=0;j<4;j++){ p[j] = (short)f2bf(a0[j]); p[4+j] = (short)f2bf(a1[j]); }
      pf[1] = p;
    }
    #pragma unroll
    for(int mf=0;mf<2;mf++)
      #pragma unroll
      for(int nf=0;nf<8;nf++)
        acc[mf][nf] = __builtin_amdgcn_mfma_f32_16x16x32_bf16(pf[mf], bv[nf], acc[mf][nf],0,0,0);
    asm volatile("" ::: "memory");
    __builtin_amdgcn_s_barrier();     // raw barrier: no vmcnt(0) drain
    asm volatile("" ::: "memory");
  }
  // epilogue: tile 63 belongs to wave 3
  if(w == 3){
    int tp = 63*32;
    *(f32x4*)(sp0 + tp)     = aw00;
    *(f32x4*)(sp0 + tp + 4) = aw01;
    *(f32x4*)(sp1 + tp)     = aw10;
    *(f32x4*)(sp1 + tp + 4) = aw11;
  }
  #pragma unroll
  for(int mf=0;mf<2;mf++)
  #pragma unroll
  for(int nf=0;nf<8;nf++)
  #pragma unroll
  for(int r=0;r<4;r++)
    outp[(row0 + mf*16 + g4*4 + r)*DDs + dv0 + nf*16 + i15] = acc[mf][nf][r];
}

extern "C" void kernel_launch(void* const* d_in, const int* in_sizes, int n_in,
                              void* d_out, int out_size, void* d_ws, size_t ws_size,
                              hipStream_t stream) {
  const float* q    = (const float*)d_in[0];
  const float* k    = (const float*)d_in[1];
  const float* v    = (const float*)d_in[2];
  const int*   mask = (const int*)d_in[3];
  const float* wsrc = (const float*)d_in[4];
  float* outp = (float*)d_out;
  float* attn = (float*)d_out + (long)NBs*TQs*DDs;
  char* ws = (char*)d_ws;
  const long NE = (long)NBs*TKs*DDs;      // 8,388,608 elements
  _Float16* kf  = (_Float16*)ws;                 // 2NE bytes
  short*    vt  = (short*)(ws + 2*NE);           // 2NE bytes
  _Float16* qwh = (_Float16*)(ws + 4*NE);        // 2NE bytes
  _Float16* qwl = (_Float16*)(ws + 6*NE);        // 2NE bytes
  float* m_ws = (float*)(ws + 8*NE);             // 32768 f32
  float* l_ws = (float*)(ws + 8*NE + 65536*4);
  unsigned long long* mbits = (unsigned long long*)(ws + 8*NE + 1048576);  // 4MB
  // wt split lives at the head of the attn region (dead before k2a overwrites it)
  short* wth = (short*)attn;
  short* wtl = (short*)attn + 262144;
  hipLaunchKernelGGL(k0_kf,          dim3(1024),    dim3(256), 0, stream, k, kf);
  hipLaunchKernelGGL(k0_mb,          dim3(2048),    dim3(256), 0, stream, mask, mbits);
  hipLaunchKernelGGL(k0_transpose_v, dim3(32,8,8),  dim3(256), 0, stream, v, vt);
  hipLaunchKernelGGL(k0_wt,          dim3(8,8),     dim3(256), 0, stream, wsrc, wth, wtl);
  hipLaunchKernelGGL(k1_qw,          dim3(128,4),   dim3(256), 0, stream, q, wth, wtl, qwh, qwl);
  hipLaunchKernelGGL(k2a,            dim3(256,2),   dim3(256), 0, stream, qwh, qwl, kf, mbits, attn, m_ws, l_ws);
  hipLaunchKernelGGL(k2b,            dim3(512),     dim3(256), 0, stream, vt, m_ws, l_ws, attn, outp);
}